// Round 25
// baseline (202.298 us; speedup 1.0000x reference)
//
#include <hip/hip_runtime.h>

// ConvLSTM2D MI355X, R25: 4 independent chains per CU. Grid 1024 =
// [b8][tile 8x8][fh2], 256 thr, __launch_bounds__(256,4) -> 16 waves/CU
// (VGPR<=128). Block = 64 px x 128 co (its fh-half of f for all 4 gates).
// Wave (pxh=w>>1, fq=w&1) = 32 px x 64 co, acc[2][4] (all 4 gates per lane).
// MFMA pipe is per-CU (m06): floor 7us/step; 2 chains/CU left it ~60% idle
// (R22=172us, MfmaUtil 28%); 4 chains interleave the serial poll/import/
// export segments. New: sibling interior exchange (each block exports its
// 64px x 32ch half; imports sibling half + 64-ch ring; polls 17 flags).
// Same proven monotonic-flag protocol; weights layout unchanged from R22.

typedef __attribute__((ext_vector_type(8))) short short8v;
typedef __attribute__((ext_vector_type(4))) float f32x4;
typedef __attribute__((ext_vector_type(4))) unsigned int u32x4;
typedef unsigned short u16;

#define HS 808             // shorts per kb block in H halo (101 x 16B slots)
#define HB 3200            // H halo base (shorts); X halo = [0, 3200)

__device__ __forceinline__ u16 f2bf(float x) {
    union { float f; unsigned u; } a; a.f = x;
    unsigned r = a.u + 0x7FFFu + ((a.u >> 16) & 1u);   // RNE
    return (u16)(r >> 16);
}
__device__ __forceinline__ float sigf(float x) { return 1.0f / (1.0f + __expf(-x)); }
__device__ __forceinline__ float tanhf_(float x) {
    float e = __expf(2.0f * x);
    return 1.0f - 2.0f / (e + 1.0f);
}

// ---- prep: weights -> staged layout + zero flags (layout = R22) ----
__global__ __launch_bounds__(256)
void prep_w(const float* __restrict__ kern, const float* __restrict__ rk,
            u16* __restrict__ wt_in, u16* __restrict__ wt_rk,
            unsigned* __restrict__ flags) {
    int idx = blockIdx.x * 256 + threadIdx.x;
    if (idx < 1024) flags[idx] = 0u;
    if (idx >= 82944) return;
    const float* s;
    u16* dst;
    if (idx < 9216) {
        int co = idx & 255, ckb = idx >> 8;          // 0..35 = tap*4+kb
        int tap = ckb >> 2, kb = ckb & 3;
        s = kern + (size_t)((tap << 5) + (kb << 3)) * 256 + co;
        dst = wt_in + (size_t)idx * 8;
    } else {
        int j = idx - 9216;
        int co = j & 255, rest = j >> 8;             // 0..287
        int kb = rest & 3, gc = rest >> 2;           // gc = g*18 + cc
        int g = gc / 18, cc = gc - g * 18;
        int tap = cc >> 1;
        int cib = (cc & 1) << 5;
        s = rk + (size_t)(((g * 9 + tap) << 6) + cib + (kb << 3)) * 256 + co;
        dst = wt_rk + (size_t)j * 8;
    }
    union { u16 u[8]; uint4 q; } o;
    #pragma unroll
    for (int i = 0; i < 8; ++i) o.u[i] = f2bf(s[i * 256]);
    *(uint4*)dst = o.q;
}

// stage X halo from f32 with in-register convert
__device__ __forceinline__ void stageXf(const float* __restrict__ src,
                                        short* __restrict__ halX,
                                        int tid, int y0, int x0) {
    #pragma unroll 2
    for (int s = tid; s < 400; s += 256) {
        int pos = s >> 2, kb = s & 3;
        int hy = pos / 10, hx = pos - hy * 10;
        int gy = y0 + hy - 1, gx = x0 + hx - 1;
        union { u16 u[8]; short8v v; } o;
        o.v = (short8v){0,0,0,0,0,0,0,0};
        if ((unsigned)gy < 64u && (unsigned)gx < 64u) {
            const float* p = src + (((gy << 6) + gx) << 5) + (kb << 3);
            float4 a0 = *(const float4*)p;
            float4 a1 = *(const float4*)(p + 4);
            o.u[0] = f2bf(a0.x); o.u[1] = f2bf(a0.y);
            o.u[2] = f2bf(a0.z); o.u[3] = f2bf(a0.w);
            o.u[4] = f2bf(a1.x); o.u[5] = f2bf(a1.y);
            o.u[6] = f2bf(a1.z); o.u[7] = f2bf(a1.w);
        }
        *(short8v*)&halX[kb * 800 + pos * 8] = o.v;
    }
}

// ---- persistent fused conv + gates, all timesteps ----
__global__ __launch_bounds__(256, 4)
void lstm_all(const float* __restrict__ xf,   // (8,10,64,64,32) f32
              const u16* __restrict__ wt_in, const u16* __restrict__ wt_rk,
              const float* __restrict__ bias, const int* __restrict__ labels,
              u16* __restrict__ hb0, u16* __restrict__ hb1,  // h ring bufs
              float* __restrict__ out, unsigned* __restrict__ flags)
{
    // X halo @0: [kb4][100][8] (3200 shorts); H halo @3200: [kb8][HS=808]
    __shared__ short hal[HB + 8 * HS];   // 9664 shorts = 19,328 B

    const int tid  = threadIdx.x;
    const int lane = tid & 63;
    const int w    = tid >> 6;
    const int pxh  = w >> 1;                   // px half: rows 0-3 / 4-7
    const int fq   = w & 1;                    // 16-f slice within fh half
    const int bid  = blockIdx.x;
    const int fh   = bid & 1;
    const int tile = (bid >> 1) & 63;
    const int b    = bid >> 7;
    const int ty = tile >> 3, tx = tile & 7;
    const int y0 = ty << 3, x0 = tx << 3;
    const int g = labels[b];

    const int co_l = lane & 15;
    const int kbl  = lane >> 4;
    const int prow = (lane & 15) >> 3, pcol = lane & 7;
    const int f = (fh << 5) + (fq << 4) + co_l;    // 0..63 global f

    float bv[4];
    #pragma unroll
    for (int n = 0; n < 4; ++n)
        bv[n] = bias[(g << 8) + (n << 6) + f];

    int aoffm[2];
    #pragma unroll
    for (int m = 0; m < 2; ++m)
        aoffm[m] = ((pxh << 2) + (m << 1) + prow) * 10 + pcol;

    int poff[2][4], loff[2][4];
    #pragma unroll
    for (int m = 0; m < 2; ++m)
        #pragma unroll
        for (int rr = 0; rr < 4; ++rr) {
            int pf = (kbl << 2) + rr;
            int ly = (pxh << 2) + (m << 1) + (pf >> 3);
            int lx = pf & 7;
            poff[m][rr] = ((((y0 + ly) << 6) + x0 + lx) << 6) + f;
            loff[m][rr] = HB + (f >> 3) * HS + ((ly + 1) * 10 + lx + 1) * 8 + (f & 7);
        }

    float cst[2][4];
    #pragma unroll
    for (int m = 0; m < 2; ++m)
        #pragma unroll
        for (int rr = 0; rr < 4; ++rr) cst[m][rr] = 0.0f;

    const float* xsrc = xf + ((size_t)b * 10 << 17);
    float*       ob0  = out + ((size_t)b * 10 << 18);
    unsigned*    myfl = flags + bid;

    // zero H halo; stage X(0)
    for (int s = tid; s < 808; s += 256)
        *(short8v*)&hal[HB + s * 8] = (short8v){0,0,0,0,0,0,0,0};
    stageXf(xsrc, hal, tid, y0, x0);
    __syncthreads();

    for (int t = 0; t < 10; ++t) {
        u16* hw = ((t & 1) ? hb1 : hb0) + ((size_t)b << 18);   // h(t)

        f32x4 acc[2][4];
        #pragma unroll
        for (int n = 0; n < 4; ++n)
            #pragma unroll
            for (int m = 0; m < 2; ++m)
                acc[m][n] = (f32x4){bv[n], bv[n], bv[n], bv[n]};

        // ---- phase X: 9 chunks (h-independent) ----
        #pragma unroll 3
        for (int tap = 0; tap < 9; ++tap) {
            const int koff = (tap / 3) * 10 + (tap % 3);
            const u16* wb = wt_in + (size_t)((((tap << 2) + kbl) << 8) + f) * 8;
            short8v bfr[4], af[2];
            #pragma unroll
            for (int n = 0; n < 4; ++n)
                bfr[n] = *(const short8v*)&wb[(size_t)n << 9];
            #pragma unroll
            for (int m = 0; m < 2; ++m)
                af[m] = *(const short8v*)&hal[kbl * 800 + (aoffm[m] + koff) * 8];
            #pragma unroll
            for (int m = 0; m < 2; ++m)
                #pragma unroll
                for (int n = 0; n < 4; ++n)
                    acc[m][n] = __builtin_amdgcn_mfma_f32_16x16x32_bf16(af[m], bfr[n], acc[m][n], 0, 0, 0);
        }

        if (t > 0) {
            // ---- poll 17 flags (wave 0): 8 spatial x 2 fh + sibling ----
            if (tid < 64) {
                bool valid = false; int fidx = 0;
                if (tid < 16) {
                    int k = tid >> 1;
                    int kk = k + (k >= 4);           // skip center
                    int nty = ty + kk / 3 - 1, ntx = tx + kk % 3 - 1;
                    valid = (unsigned)nty < 8u && (unsigned)ntx < 8u;
                    fidx = (b << 7) + ((((nty << 3) + ntx) << 1) | (tid & 1));
                } else if (tid == 16) {
                    valid = true;
                    fidx = (b << 7) + (tile << 1) + (1 - fh);   // sibling
                }
                unsigned tgt = (unsigned)t;
                int guard = 0;
                for (;;) {
                    unsigned vv = tgt;
                    if (valid)
                        vv = __hip_atomic_load(flags + fidx, __ATOMIC_RELAXED,
                                               __HIP_MEMORY_SCOPE_SYSTEM);
                    if (__all(vv >= tgt)) break;
                    if (++guard > (1 << 19)) break;
                    __builtin_amdgcn_s_sleep(2);
                }
            }
            __syncthreads();   // h(t-1) exports of all producers visible

            const u16* hr = ((t & 1) ? hb0 : hb1) + ((size_t)b << 18);
            // ---- import ring h(t-1): 36 px x 8 units, sc0sc1 16B ----
            #pragma unroll
            for (int u = 0; u < 2; ++u) {
                int s = tid + (u << 8);
                if (s < 288) {
                    int posr = s >> 3, kb = s & 7;
                    int hy, hx;
                    if (posr < 10)      { hy = 0; hx = posr; }
                    else if (posr < 20) { hy = 9; hx = posr - 10; }
                    else { int v = posr - 20; hy = 1 + (v >> 1); hx = (v & 1) * 9; }
                    int gy = y0 + hy - 1, gx = x0 + hx - 1;
                    bool inb = (unsigned)gy < 64u && (unsigned)gx < 64u;
                    const u16* ga = inb ? (hr + (((gy << 6) + gx) << 6) + (kb << 3)) : hr;
                    u32x4 v;
                    asm volatile("global_load_dwordx4 %0, %1, off sc0 sc1"
                                 : "=v"(v) : "v"(ga) : "memory");
                    asm volatile("s_waitcnt vmcnt(0)" ::: "memory");
                    __builtin_amdgcn_sched_barrier(0);
                    if (!inb) v = (u32x4){0u, 0u, 0u, 0u};
                    *(u32x4*)&hal[HB + kb * HS + (hy * 10 + hx) * 8] = v;
                }
            }
            // ---- import sibling interior half: 64 px x 4 units ----
            {
                int px = tid >> 2;
                int kbu = ((1 - fh) << 2) + (tid & 3);
                int py = px >> 3, pxx = px & 7;
                const u16* ga = hr + ((((y0 + py) << 6) + x0 + pxx) << 6) + (kbu << 3);
                u32x4 v;
                asm volatile("global_load_dwordx4 %0, %1, off sc0 sc1"
                             : "=v"(v) : "v"(ga) : "memory");
                asm volatile("s_waitcnt vmcnt(0)" ::: "memory");
                __builtin_amdgcn_sched_barrier(0);
                *(u32x4*)&hal[HB + kbu * HS + ((py + 1) * 10 + pxx + 1) * 8] = v;
            }
            __syncthreads();   // full 64-ch H halo in LDS

            // ---- phase H: 18 chunks ----
            #pragma unroll 3
            for (int c = 0; c < 18; ++c) {
                const int tap = c >> 1;
                const int koff = (tap / 3) * 10 + (tap % 3);
                const u16* wb = wt_rk + (size_t)(((((g * 18 + c) << 2) + kbl) << 8) + f) * 8;
                short8v bfr[4], af[2];
                #pragma unroll
                for (int n = 0; n < 4; ++n)
                    bfr[n] = *(const short8v*)&wb[(size_t)n << 9];
                const int abase = HB + (((c & 1) << 2) + kbl) * HS;
                #pragma unroll
                for (int m = 0; m < 2; ++m)
                    af[m] = *(const short8v*)&hal[abase + (aoffm[m] + koff) * 8];
                #pragma unroll
                for (int m = 0; m < 2; ++m)
                    #pragma unroll
                    for (int n = 0; n < 4; ++n)
                        acc[m][n] = __builtin_amdgcn_mfma_f32_16x16x32_bf16(af[m], bfr[n], acc[m][n], 0, 0, 0);
            }
        }
        __syncthreads();   // sync1: H-LDS (h(t-1)) reads complete

        // ---- gates + out store + h(t) own-half interior -> LDS ----
        float* ob = ob0 + ((size_t)t << 18);
        #pragma unroll
        for (int m = 0; m < 2; ++m) {
            #pragma unroll
            for (int rr = 0; rr < 4; ++rr) {
                float zi = acc[m][0][rr], zf = acc[m][1][rr];
                float zg = acc[m][2][rr], zo = acc[m][3][rr];
                float cn = sigf(zf) * cst[m][rr] + sigf(zi) * tanhf_(zg);
                float hn = sigf(zo) * tanhf_(cn);
                cst[m][rr] = cn;
                ob[poff[m][rr]] = hn;
                hal[loff[m][rr]] = (short)f2bf(hn);
            }
        }
        __syncthreads();   // sync2: own-half interior h(t) in LDS

        if (t < 9) {
            // ---- export own half tile: 64 px x 4 units, sc0sc1 16B ----
            {
                int px = tid >> 2;
                int kbu = (fh << 2) + (tid & 3);
                int py = px >> 3, pxx = px & 7;
                u32x4 v = *(const u32x4*)&hal[HB + kbu * HS + ((py + 1) * 10 + pxx + 1) * 8];
                const u16* ga = hw + ((((y0 + py) << 6) + x0 + pxx) << 6) + (kbu << 3);
                asm volatile("global_store_dwordx4 %0, %1, off sc0 sc1"
                             :: "v"(ga), "v"(v) : "memory");
            }
            // ---- stage X(t+1) from f32 (overlaps export latency) ----
            stageXf(xsrc + ((size_t)(t + 1) << 17), hal, tid, y0, x0);
            asm volatile("s_waitcnt vmcnt(0)" ::: "memory");  // exports drained
            __syncthreads();   // sync3: exports + X(t+1) staged
            if (tid == 0)
                __hip_atomic_fetch_add(myfl, 1u, __ATOMIC_RELAXED,
                                       __HIP_MEMORY_SCOPE_SYSTEM);
        }
    }
}

extern "C" void kernel_launch(void* const* d_in, const int* in_sizes, int n_in,
                              void* d_out, int out_size, void* d_ws, size_t ws_size,
                              hipStream_t stream)
{
    const float* x    = (const float*)d_in[0];
    const int*   lbl  = (const int*)  d_in[1];
    const float* kern = (const float*)d_in[2];
    const float* rk   = (const float*)d_in[3];
    const float* bias = (const float*)d_in[4];
    float* out = (float*)d_out;

    // ws: hb0 4.19MB | hb1 4.19MB | wt_in 0.147 | wt_rk 1.18 | flags 4KB
    u16* hb0   = (u16*)d_ws;
    u16* hb1   = hb0 + 2097152;
    u16* wt_in = hb1 + 2097152;
    u16* wt_rk = wt_in + 73728;
    unsigned* flags = (unsigned*)(wt_rk + 589824);

    hipLaunchKernelGGL(prep_w, dim3(324), dim3(256), 0, stream,
                       kern, rk, wt_in, wt_rk, flags);

    // Regular launch; co-residency by __launch_bounds__(256, 4) capacity
    // (4 blocks/CU x 256 CUs = 1024 blocks exactly; VGPR<=128, LDS 4x19.3KB).
    hipLaunchKernelGGL(lstm_all, dim3(1024), dim3(256), 0, stream,
                       x, wt_in, wt_rk, bias, lbl, hb0, hb1, out, flags);
}

// Round 26
// 169.453 us; speedup vs baseline: 1.1938x; 1.1938x over previous
//
#include <hip/hip_runtime.h>

// ConvLSTM2D MI355X, R26: R22 anchor (172us) + batched ring import.
// R22 ran 2x {issue sc0sc1 load -> vmcnt(0) -> LDS write} serially (the 2nd
// ~900cyc bypass load couldn't issue until the 1st drained). Now: issue both
// loads, ONE vmcnt(0), write both — tight window (no MFMAs inside; R17-scale,
// not R21's hazard). Saves ~900cyc/step serial latency.
// All else identical to R22: 512 blk x 256 thr (2 independent blocks/CU),
// local 8-neighbor flag sync, h interior in LDS, c in regs, X staged from f32.
// Failed-and-reverted ledger: R18 pad/cvt, R19 full unroll (spill), R20
// 32x32 MFMA, R21/R23 import-hiding (asm-liveness / VGPR spill), R24 flag
// reorder, R25 fh-split 4-chains (coherent-traffic blowup).

typedef __attribute__((ext_vector_type(8))) short short8v;
typedef __attribute__((ext_vector_type(4))) float f32x4;
typedef __attribute__((ext_vector_type(4))) unsigned int u32x4;
typedef unsigned short u16;

#define HS 808             // shorts per kb block in H halo (101 x 16B slots)
#define HB 3200            // H halo base (shorts); X halo = [0, 3200)

__device__ __forceinline__ u16 f2bf(float x) {
    union { float f; unsigned u; } a; a.f = x;
    unsigned r = a.u + 0x7FFFu + ((a.u >> 16) & 1u);   // RNE
    return (u16)(r >> 16);
}
__device__ __forceinline__ float sigf(float x) { return 1.0f / (1.0f + __expf(-x)); }
__device__ __forceinline__ float tanhf_(float x) {
    float e = __expf(2.0f * x);
    return 1.0f - 2.0f / (e + 1.0f);
}

// ---- prep: weights -> staged layout + zero flags ----
__global__ __launch_bounds__(256)
void prep_w(const float* __restrict__ kern, const float* __restrict__ rk,
            u16* __restrict__ wt_in, u16* __restrict__ wt_rk,
            unsigned* __restrict__ flags) {
    int idx = blockIdx.x * 256 + threadIdx.x;
    if (idx < 512) flags[idx] = 0u;
    if (idx >= 82944) return;
    const float* s;
    u16* dst;
    if (idx < 9216) {
        int co = idx & 255, ckb = idx >> 8;          // 0..35 = tap*4+kb
        int tap = ckb >> 2, kb = ckb & 3;
        s = kern + (size_t)((tap << 5) + (kb << 3)) * 256 + co;
        dst = wt_in + (size_t)idx * 8;
    } else {
        int j = idx - 9216;
        int co = j & 255, rest = j >> 8;             // 0..287
        int kb = rest & 3, gc = rest >> 2;           // gc = g*18 + cc
        int g = gc / 18, cc = gc - g * 18;
        int tap = cc >> 1;
        int cib = (cc & 1) << 5;
        s = rk + (size_t)(((g * 9 + tap) << 6) + cib + (kb << 3)) * 256 + co;
        dst = wt_rk + (size_t)j * 8;
    }
    union { u16 u[8]; uint4 q; } o;
    #pragma unroll
    for (int i = 0; i < 8; ++i) o.u[i] = f2bf(s[i * 256]);
    *(uint4*)dst = o.q;
}

// stage X halo from f32 with in-register convert (no prep_x pass)
__device__ __forceinline__ void stageXf(const float* __restrict__ src,
                                        short* __restrict__ halX,
                                        int tid, int y0, int x0) {
    #pragma unroll 2
    for (int s = tid; s < 400; s += 256) {
        int pos = s >> 2, kb = s & 3;
        int hy = pos / 10, hx = pos - hy * 10;
        int gy = y0 + hy - 1, gx = x0 + hx - 1;
        union { u16 u[8]; short8v v; } o;
        o.v = (short8v){0,0,0,0,0,0,0,0};
        if ((unsigned)gy < 64u && (unsigned)gx < 64u) {
            const float* p = src + (((gy << 6) + gx) << 5) + (kb << 3);
            float4 a0 = *(const float4*)p;
            float4 a1 = *(const float4*)(p + 4);
            o.u[0] = f2bf(a0.x); o.u[1] = f2bf(a0.y);
            o.u[2] = f2bf(a0.z); o.u[3] = f2bf(a0.w);
            o.u[4] = f2bf(a1.x); o.u[5] = f2bf(a1.y);
            o.u[6] = f2bf(a1.z); o.u[7] = f2bf(a1.w);
        }
        *(short8v*)&halX[kb * 800 + pos * 8] = o.v;
    }
}

// ---- persistent fused conv + gates, all timesteps ----
__global__ __launch_bounds__(256, 2)
void lstm_all(const float* __restrict__ xf,   // (8,10,64,64,32) f32
              const u16* __restrict__ wt_in, const u16* __restrict__ wt_rk,
              const float* __restrict__ bias, const int* __restrict__ labels,
              u16* __restrict__ hb0, u16* __restrict__ hb1,  // h ring bufs
              float* __restrict__ out, unsigned* __restrict__ flags)
{
    // X halo @0: [kb4][100][8] (3200 shorts); H halo @3200: [kb8][HS=808]
    __shared__ short hal[HB + 8 * HS];   // 9664 shorts = 19,328 B

    const int tid  = threadIdx.x;
    const int lane = tid & 63;
    const int wq   = tid >> 6;                 // wave = f-slice 0..3
    const int b    = blockIdx.x >> 6;
    const int tile = blockIdx.x & 63;
    const int ty = tile >> 3, tx = tile & 7;
    const int y0 = ty << 3, x0 = tx << 3;
    const int g = labels[b];

    const int co_l = lane & 15;
    const int kbl  = lane >> 4;
    const int prow = (lane & 15) >> 3, pcol = lane & 7;
    const int f = (wq << 4) + co_l;

    float bv[4];
    #pragma unroll
    for (int n = 0; n < 4; ++n)
        bv[n] = bias[(g << 8) + (n << 6) + f];

    int aoffm[4];
    #pragma unroll
    for (int m = 0; m < 4; ++m)
        aoffm[m] = ((m << 1) + prow) * 10 + pcol;

    int poff[4][4], loff[4][4];
    #pragma unroll
    for (int m = 0; m < 4; ++m)
        #pragma unroll
        for (int rr = 0; rr < 4; ++rr) {
            int pf = (kbl << 2) + rr;
            int ly = (m << 1) + (pf >> 3);
            int lx = pf & 7;
            poff[m][rr] = ((((y0 + ly) << 6) + x0 + lx) << 6) + f;
            loff[m][rr] = HB + (f >> 3) * HS + ((ly + 1) * 10 + lx + 1) * 8 + (f & 7);
        }

    // ring-import geometry (unit A = tid < 288 always true; unit B tid < 32)
    int ilA, ilB = 0;
    bool inA, inB = false;
    const bool okB = tid < 32;
    long offA, offB = 0;
    {
        int posr = tid >> 3, kb = tid & 7;
        int hy, hx;
        if (posr < 10)      { hy = 0; hx = posr; }
        else if (posr < 20) { hy = 9; hx = posr - 10; }
        else { int v = posr - 20; hy = 1 + (v >> 1); hx = (v & 1) * 9; }
        int gy = y0 + hy - 1, gx = x0 + hx - 1;
        inA = (unsigned)gy < 64u && (unsigned)gx < 64u;
        offA = inA ? (long)((((gy << 6) + gx) << 6) + (kb << 3)) : 0;
        ilA = HB + kb * HS + (hy * 10 + hx) * 8;
    }
    if (okB) {
        int s = tid + 256;
        int posr = s >> 3, kb = s & 7;
        int v = posr - 20;
        int hy = 1 + (v >> 1), hx = (v & 1) * 9;
        int gy = y0 + hy - 1, gx = x0 + hx - 1;
        inB = (unsigned)gy < 64u && (unsigned)gx < 64u;
        offB = inB ? (long)((((gy << 6) + gx) << 6) + (kb << 3)) : 0;
        ilB = HB + kb * HS + (hy * 10 + hx) * 8;
    }

    float cst[4][4];
    #pragma unroll
    for (int m = 0; m < 4; ++m)
        #pragma unroll
        for (int rr = 0; rr < 4; ++rr) cst[m][rr] = 0.0f;

    const float* xsrc = xf + ((size_t)b * 10 << 17);
    float*       ob0  = out + ((size_t)b * 10 << 18);
    unsigned*    myfl = flags + (b << 6) + tile;

    // zero H halo (out-of-image ring cells stay 0 forever); stage X(0)
    for (int s = tid; s < 808; s += 256)
        *(short8v*)&hal[HB + s * 8] = (short8v){0,0,0,0,0,0,0,0};
    stageXf(xsrc, hal, tid, y0, x0);
    __syncthreads();

    for (int t = 0; t < 10; ++t) {
        u16* hw = ((t & 1) ? hb1 : hb0) + ((size_t)b << 18);   // h(t)

        f32x4 acc[4][4];
        #pragma unroll
        for (int n = 0; n < 4; ++n)
            #pragma unroll
            for (int m = 0; m < 4; ++m)
                acc[m][n] = (f32x4){bv[n], bv[n], bv[n], bv[n]};

        // ---- phase X: 9 chunks (h-independent) ----
        #pragma unroll 3
        for (int tap = 0; tap < 9; ++tap) {
            const int koff = (tap / 3) * 10 + (tap % 3);
            const u16* wb = wt_in + (size_t)((((tap << 2) + kbl) << 8) + f) * 8;
            short8v bfr[4], af[4];
            #pragma unroll
            for (int n = 0; n < 4; ++n)
                bfr[n] = *(const short8v*)&wb[(size_t)n << 9];
            #pragma unroll
            for (int m = 0; m < 4; ++m)
                af[m] = *(const short8v*)&hal[kbl * 800 + (aoffm[m] + koff) * 8];
            #pragma unroll
            for (int m = 0; m < 4; ++m)
                #pragma unroll
                for (int n = 0; n < 4; ++n)
                    acc[m][n] = __builtin_amdgcn_mfma_f32_16x16x32_bf16(af[m], bfr[n], acc[m][n], 0, 0, 0);
        }

        if (t > 0) {
            // ---- poll 8 neighbor flags (wave 0): need h(t-1) exported ----
            if (tid < 64) {
                bool valid = false; int fidx = 0;
                if (tid < 8) {
                    int kk = tid + (tid >= 4);       // 0..8 skipping center
                    int nty = ty + kk / 3 - 1, ntx = tx + kk % 3 - 1;
                    valid = (unsigned)nty < 8u && (unsigned)ntx < 8u;
                    fidx = (b << 6) + (nty << 3) + ntx;
                }
                unsigned tgt = (unsigned)t;
                int guard = 0;
                for (;;) {
                    unsigned vv = tgt;
                    if (valid)
                        vv = __hip_atomic_load(flags + fidx, __ATOMIC_RELAXED,
                                               __HIP_MEMORY_SCOPE_SYSTEM);
                    if (__all(vv >= tgt)) break;
                    if (++guard > (1 << 19)) break;
                    __builtin_amdgcn_s_sleep(2);
                }
            }
            __syncthreads();   // neighbors' h(t-1) rings globally visible

            // ---- import ring h(t-1): BATCHED (issue both, drain once) ----
            {
                const u16* hr = ((t & 1) ? hb0 : hb1) + ((size_t)b << 18);
                u32x4 vA, vB;
                const u16* gaA = hr + offA;
                asm volatile("global_load_dwordx4 %0, %1, off sc0 sc1"
                             : "=v"(vA) : "v"(gaA) : "memory");
                if (okB) {
                    const u16* gaB = hr + offB;
                    asm volatile("global_load_dwordx4 %0, %1, off sc0 sc1"
                                 : "=v"(vB) : "v"(gaB) : "memory");
                }
                asm volatile("s_waitcnt vmcnt(0)" ::: "memory");
                __builtin_amdgcn_sched_barrier(0);
                if (!inA) vA = (u32x4){0u, 0u, 0u, 0u};
                *(u32x4*)&hal[ilA] = vA;
                if (okB) {
                    if (!inB) vB = (u32x4){0u, 0u, 0u, 0u};
                    *(u32x4*)&hal[ilB] = vB;
                }
            }
            __syncthreads();   // ring in LDS

            // ---- phase H: 18 chunks ----
            #pragma unroll 3
            for (int c = 0; c < 18; ++c) {
                const int tap = c >> 1;
                const int koff = (tap / 3) * 10 + (tap % 3);
                const u16* wb = wt_rk + (size_t)(((((g * 18 + c) << 2) + kbl) << 8) + f) * 8;
                short8v bfr[4], af[4];
                #pragma unroll
                for (int n = 0; n < 4; ++n)
                    bfr[n] = *(const short8v*)&wb[(size_t)n << 9];
                const int abase = HB + (((c & 1) << 2) + kbl) * HS;
                #pragma unroll
                for (int m = 0; m < 4; ++m)
                    af[m] = *(const short8v*)&hal[abase + (aoffm[m] + koff) * 8];
                #pragma unroll
                for (int m = 0; m < 4; ++m)
                    #pragma unroll
                    for (int n = 0; n < 4; ++n)
                        acc[m][n] = __builtin_amdgcn_mfma_f32_16x16x32_bf16(af[m], bfr[n], acc[m][n], 0, 0, 0);
            }
        }
        __syncthreads();   // sync1: H-LDS (h(t-1)) reads complete

        // ---- gates + out store + h(t) interior -> LDS ----
        float* ob = ob0 + ((size_t)t << 18);
        #pragma unroll
        for (int m = 0; m < 4; ++m) {
            #pragma unroll
            for (int rr = 0; rr < 4; ++rr) {
                float zi = acc[m][0][rr], zf = acc[m][1][rr];
                float zg = acc[m][2][rr], zo = acc[m][3][rr];
                float cn = sigf(zf) * cst[m][rr] + sigf(zi) * tanhf_(zg);
                float hn = sigf(zo) * tanhf_(cn);
                cst[m][rr] = cn;
                ob[poff[m][rr]] = hn;
                hal[loff[m][rr]] = (short)f2bf(hn);
            }
        }
        __syncthreads();   // sync2: interior h(t) in LDS

        if (t < 9) {
            // ---- ring export: 28 boundary px x 8 units, sc0sc1 16B ----
            if (tid < 224) {
                int pxr = tid >> 3, kb = tid & 7;
                int dy, dx;
                if (pxr < 8)       { dy = 0; dx = pxr; }
                else if (pxr < 16) { dy = 7; dx = pxr - 8; }
                else { int v = pxr - 16; dy = 1 + (v >> 1); dx = (v & 1) * 7; }
                u32x4 v = *(const u32x4*)&hal[HB + kb * HS + ((dy + 1) * 10 + dx + 1) * 8];
                const u16* ga = hw + ((((y0 + dy) << 6) + x0 + dx) << 6) + (kb << 3);
                asm volatile("global_store_dwordx4 %0, %1, off sc0 sc1"
                             :: "v"(ga), "v"(v) : "memory");
            }
            // ---- stage X(t+1) from f32 (overlaps export latency) ----
            stageXf(xsrc + ((size_t)(t + 1) << 17), hal, tid, y0, x0);
            asm volatile("s_waitcnt vmcnt(0)" ::: "memory");  // exports drained
            __syncthreads();   // sync3: exports + X(t+1) staged
            if (tid == 0)
                __hip_atomic_fetch_add(myfl, 1u, __ATOMIC_RELAXED,
                                       __HIP_MEMORY_SCOPE_SYSTEM);
        }
    }
}

extern "C" void kernel_launch(void* const* d_in, const int* in_sizes, int n_in,
                              void* d_out, int out_size, void* d_ws, size_t ws_size,
                              hipStream_t stream)
{
    const float* x    = (const float*)d_in[0];
    const int*   lbl  = (const int*)  d_in[1];
    const float* kern = (const float*)d_in[2];
    const float* rk   = (const float*)d_in[3];
    const float* bias = (const float*)d_in[4];
    float* out = (float*)d_out;

    // ws: hb0 4.19MB | hb1 4.19MB | wt_in 0.147 | wt_rk 1.18 | flags 2KB
    u16* hb0   = (u16*)d_ws;
    u16* hb1   = hb0 + 2097152;
    u16* wt_in = hb1 + 2097152;
    u16* wt_rk = wt_in + 73728;
    unsigned* flags = (unsigned*)(wt_rk + 589824);

    hipLaunchKernelGGL(prep_w, dim3(324), dim3(256), 0, stream,
                       kern, rk, wt_in, wt_rk, flags);

    // Regular launch; co-residency guaranteed by __launch_bounds__(256, 2)
    // capacity (2 blocks/CU x 256 CUs = 512 blocks exactly; guide §1).
    hipLaunchKernelGGL(lstm_all, dim3(512), dim3(256), 0, stream,
                       x, wt_in, wt_rk, bias, lbl, hb0, hb1, out, flags);
}